// Round 7
// baseline (171.099 us; speedup 1.0000x reference)
//
#include <hip/hip_runtime.h>

#define NB 4
#define NS 2048
#define ND 768
#define NH 12
#define NDH 64
#define XPITCH 72
#define SSCALE 0.18033688011112043f   // (1/sqrt(64)) * log2(e)

typedef __bf16 bf16x8 __attribute__((ext_vector_type(8)));
typedef float  f32x4  __attribute__((ext_vector_type(4)));
typedef unsigned int u32;

#define MFMA16(a, b, c) __builtin_amdgcn_mfma_f32_16x16x32_bf16(a, b, c, 0, 0, 0)

__device__ __forceinline__ u32 packbf(float a, float b) {
    u32 ua = __builtin_bit_cast(u32, a) + 0x8000u;
    u32 ub = __builtin_bit_cast(u32, b) + 0x8000u;
    return __builtin_amdgcn_perm(ub, ua, 0x07060302u);
}

__device__ __forceinline__ bf16x8 cvt8(float4 a, float4 b) {
    union { u32 u[4]; bf16x8 v; } r;
    r.u[0] = packbf(a.x, a.y); r.u[1] = packbf(a.z, a.w);
    r.u[2] = packbf(b.x, b.y); r.u[3] = packbf(b.z, b.w);
    return r.v;
}

__device__ __forceinline__ __bf16 f2bf(float f) {
    u32 u = __builtin_bit_cast(u32, f) + 0x8000u;
    unsigned short s = (unsigned short)(u >> 16);
    return __builtin_bit_cast(__bf16, s);
}

// HW DMA global->LDS, 16B per lane. LDS dest must be the WAVE-UNIFORM lane-0
// base; HW adds lane*16B. Global source is per-lane.
__device__ __forceinline__ void gl16(const __bf16* g, __bf16* l) {
    __builtin_amdgcn_global_load_lds(
        (const __attribute__((address_space(1))) unsigned int*)g,
        (__attribute__((address_space(3))) unsigned int*)l,
        16, 0, 0);
}

// ---------------------------------------------------------------------------
// Workspace layouts — ALL fragment-major, ALL R4-hardware-verified:
//   Q: bh*131072 + qt*4096 + nt*1024 + j*512 + lane*8     (nt: 16-row group)
//   K: bh*131072 + sigma*2048 + mt*1024 + j*512 + lane*8  (sigma: 32-row slab)
//   V: bh*131072 + sigma*2048 + dt*512           + lane*8 (same 32-col slabs)
// The attn K-loop reads 32-row slabs sigma = kt*2 + wk — the SAME linear
// slab order the old 4-way split used (sigma = kt128*4 + w). No proj change.
// ---------------------------------------------------------------------------

// ---------------------------------------------------------------------------
// Kernel 1: QKV projections — R4/R6 VERBATIM (hardware-verified, coalesced
// fragment-major stores for Q, K, and V).
// ---------------------------------------------------------------------------
__global__ __launch_bounds__(256, 4) void proj_kernel(
    const float* __restrict__ x,
    const float* __restrict__ wq, const float* __restrict__ bq,
    const float* __restrict__ wk, const float* __restrict__ bk,
    const float* __restrict__ wv, const float* __restrict__ bv,
    __bf16* __restrict__ qws, __bf16* __restrict__ kws, __bf16* __restrict__ vtws)
{
    const int st = blockIdx.x, h = blockIdx.y, b = blockIdx.z;
    const int s0 = st * 64;
    const int tid = threadIdx.x;

    __shared__ __align__(16) __bf16 Xs[64 * XPITCH];
    __shared__ __align__(16) __bf16 Tv[64 * XPITCH];

    const int r = tid >> 2, f = tid & 3;
    const int lane = tid & 63, w = tid >> 6, col = lane & 15, quad = lane >> 4;

    const size_t wrow = (size_t)(h * NDH + w * 16 + col) * NDH;
    const float* wq0 = wq + wrow + quad * 8;
    const float* wk0 = wk + wrow + quad * 8;
    const float* wv0 = wv + wrow + quad * 8;
    const bf16x8 wqa0 = cvt8(*(const float4*)(wq0),      *(const float4*)(wq0 + 4));
    const bf16x8 wqa1 = cvt8(*(const float4*)(wq0 + 32), *(const float4*)(wq0 + 36));
    const bf16x8 wka0 = cvt8(*(const float4*)(wk0),      *(const float4*)(wk0 + 4));
    const bf16x8 wka1 = cvt8(*(const float4*)(wk0 + 32), *(const float4*)(wk0 + 36));
    const bf16x8 wva0 = cvt8(*(const float4*)(wv0),      *(const float4*)(wv0 + 4));
    const bf16x8 wva1 = cvt8(*(const float4*)(wv0 + 32), *(const float4*)(wv0 + 36));

    float bqs[4], bks[4], bvs[4];
#pragma unroll
    for (int rr = 0; rr < 4; ++rr) {
        const int e = h * NDH + w * 16 + quad * 4 + rr;
        bqs[rr] = bq[e] * SSCALE;
        bks[rr] = bk[e];
        bvs[rr] = bv[e];
    }

    const size_t bh = (size_t)(b * NH + h);

    {
        const float* xrow = x + (size_t)(b * NS + s0 + r) * ND + h * NDH + f * 16;
        const float4 v0 = *(const float4*)(xrow);
        const float4 v1 = *(const float4*)(xrow + 4);
        const float4 v2 = *(const float4*)(xrow + 8);
        const float4 v3 = *(const float4*)(xrow + 12);
        *(bf16x8*)&Xs[r * XPITCH + f * 16]     = cvt8(v0, v1);
        *(bf16x8*)&Xs[r * XPITCH + f * 16 + 8] = cvt8(v2, v3);
    }
    __syncthreads();

    // lane-constant pieces of the fragment-layout address (e-side):
    // e0 = w*16 + quad*4 = 32*jj + 8*qa + 4*hf
    const int e0 = w * 16 + quad * 4;
    const int jj = e0 >> 5;            // j (0/1)
    const int qa = (e0 >> 3) & 3;      // quad_attn
    const int hf = (e0 >> 2) & 1;      // which uint2 half of the 16B chunk
    const int Lf = qa * 16 + col;      // fragment lane
    const int kt = st >> 1;            // 128-row K-tile index

#pragma unroll
    for (int nt = 0; nt < 4; ++nt) {
        const bf16x8 xb0 = *(const bf16x8*)&Xs[(nt * 16 + col) * XPITCH + quad * 8];
        const bf16x8 xb1 = *(const bf16x8*)&Xs[(nt * 16 + col) * XPITCH + 32 + quad * 8];
        f32x4 aq = {0.f, 0.f, 0.f, 0.f};
        f32x4 ak = {0.f, 0.f, 0.f, 0.f};
        f32x4 av = {0.f, 0.f, 0.f, 0.f};
        aq = MFMA16(wqa0, xb0, aq); aq = MFMA16(wqa1, xb1, aq);
        ak = MFMA16(wka0, xb0, ak); ak = MFMA16(wka1, xb1, ak);
        av = MFMA16(wva0, xb0, av); av = MFMA16(wva1, xb1, av);

        union { u32 u[2]; uint2 v; } pq, pk;
        pq.u[0] = packbf(fmaf(aq[0], SSCALE, bqs[0]), fmaf(aq[1], SSCALE, bqs[1]));
        pq.u[1] = packbf(fmaf(aq[2], SSCALE, bqs[2]), fmaf(aq[3], SSCALE, bqs[3]));
        pk.u[0] = packbf(ak[0] + bks[0], ak[1] + bks[1]);
        pk.u[1] = packbf(ak[2] + bks[2], ak[3] + bks[3]);

        // fragment-major stores (R4-verified)
        const int wa = (st & 1) * 2 + (nt >> 1);   // 32-row slab within 128-tile
        const int mt = nt & 1;
        const size_t kidx = ((((((size_t)bh * 16 + kt) * 4 + wa) * 2 + mt) * 2 + jj) * 64 + Lf) * 8 + hf * 4;
        const size_t qidx = (((((size_t)bh * 32 + st) * 4 + nt) * 2 + jj) * 64 + Lf) * 8 + hf * 4;
        *(uint2*)(kws + kidx) = pk.v;
        *(uint2*)(qws + qidx) = pq.v;

        const int pos = ((nt >> 1) << 5) + ((col >> 2) << 3) + ((nt & 1) << 2) + (col & 3);
#pragma unroll
        for (int rr = 0; rr < 4; ++rr)
            Tv[(w * 16 + quad * 4 + rr) * XPITCH + pos] = f2bf(av[rr] + bvs[rr]);
    }
    __syncthreads();

    {
        const uint4 v0 = *(const uint4*)&Tv[r * XPITCH + f * 16];
        const uint4 v1 = *(const uint4*)&Tv[r * XPITCH + f * 16 + 8];
        // thread (r,f) holds V^T[d=r][s0 + f*16 .. +15] = two 8-s chunks (R4-verified)
        const int wv_ = (st & 1) * 2 + (f >> 1);
        const int dtv = r >> 4;
        const int colv = r & 15;
        const int L0 = ((f & 1) * 2 + 0) * 16 + colv;
        const int L1 = ((f & 1) * 2 + 1) * 16 + colv;
        const size_t vbase = (((size_t)bh * 16 + kt) * 4 + wv_) * 4 + dtv;
        *(uint4*)(vtws + (vbase * 64 + L0) * 8) = v0;
        *(uint4*)(vtws + (vbase * 64 + L1) * 8) = v1;
    }
}

// ---------------------------------------------------------------------------
// Kernel 2: flash attention WITHOUT online max (scores statically bounded;
// exp2 direct). NEW wave decomposition for occupancy (R6 counters: all pipes
// <45%, occupancy 28% — latency-bound; acc tile was the register pin):
//   waves (wq,wk) in 2x2: each computes 32 q-rows x 32 k-row slices.
//   acc o[4][2] = 32 AGPR (was 64), qb = 16 (was 32) -> ~100 unified,
//   so __launch_bounds__(256,4) is register-safe (R2 cliff: 4 blocks only
//   spill when unified > 128; here arch ~70 + 32 acc).
//   K-tile = 64 rows, NT = 32. Waves wq=0,1 with the same wk duplicate-DMA
//   the same 4KB slab into private LDS (benign, preserves the barrier-free
//   wave-private structure; 2x L2 reads ~ 18 TB/s << 34.5 ceiling).
// Staging: global_load_lds DMA (R6-proven, zero staging registers); K/V
// fragment-major slabs are the SAME layout the 4-way split used (sigma
// relabeling only) -> proj unchanged.
// s_setprio OUT (R3). XCD-bijective decode kept (R3: FETCH 109->24MB).
// LDS: K [0,16K) | V [16K,32K) | lbuf [32768,33280); epilogue slab aliases
// [0,17408). Total 33280 B -> 4 blocks = 133 KB <= 160 KB.
// ---------------------------------------------------------------------------
__global__ __launch_bounds__(256, 4) void attn_kernel(
    const __bf16* __restrict__ qws, const __bf16* __restrict__ kws,
    const __bf16* __restrict__ vtws, float* __restrict__ out)
{
    // XCD-aware bijective decode: bid = xcd + 8*j, j = 32*(group within XCD) + qt
    const int bid = blockIdx.x;
    const int xcd = bid & 7;
    const int j   = bid >> 3;            // 0..191
    const int g   = xcd * 6 + (j >> 5);  // (b,h) group 0..47
    const int qt  = j & 31;
    const int h   = g % NH;
    const int b   = g / NH;

    const int q0 = qt * 64;
    const int tid = threadIdx.x;

    __shared__ __align__(16) unsigned char smem[33280];
    __bf16* ldsK = (__bf16*)smem;                // 16 KB, wave w at [w*2048, +2048) elems
    __bf16* ldsV = (__bf16*)(smem + 16384);      // 16 KB
    float* slab  = (float*)smem;                 // 64 x 68 f32 (epilogue, aliases K/V)
    float* lbuf  = (float*)(smem + 32768);       // 128 f32 (no alias)

    const size_t bh = (size_t)(b * NH + h);
    const int lane = tid & 63, w = tid >> 6, col = lane & 15, quad = lane >> 4;
    const int wq = w >> 1, wk = w & 1;

    // Q fragments: this wave's 32 q-rows (nt in {0,1} -> rows wq*32+nt*16+col)
    bf16x8 qb0[2], qb1[2];
    {
        const __bf16* qp = qws + (size_t)bh * 131072 + (size_t)qt * 4096
                         + wq * 2048 + lane * 8;
#pragma unroll
        for (int nt = 0; nt < 2; ++nt) {
            qb0[nt] = *(const bf16x8*)(qp + nt * 1024);
            qb1[nt] = *(const bf16x8*)(qp + nt * 1024 + 512);
        }
    }

    // fragment-major global bases: slab sigma = kt*2 + wk (32 rows each)
    const __bf16* kg = kws  + (size_t)bh * 131072 + wk * 2048 + lane * 8;  // per-lane src
    const __bf16* vg = vtws + (size_t)bh * 131072 + wk * 2048 + lane * 8;
    __bf16* lk  = ldsK + w * 2048;              // wave-uniform DMA dest base
    __bf16* lv  = ldsV + w * 2048;
    const __bf16* lkr = lk + lane * 8;          // per-lane read base
    const __bf16* lvr = lv + lane * 8;

    float l[2] = {0.f, 0.f};
    f32x4 o[4][2];
#pragma unroll
    for (int dt = 0; dt < 4; ++dt)
#pragma unroll
        for (int nt = 0; nt < 2; ++nt) o[dt][nt] = (f32x4){0.f, 0.f, 0.f, 0.f};

    // ---- prologue: DMA tile 0 into wave-private slabs (no regs, no barrier)
#pragma unroll
    for (int i = 0; i < 4; ++i) gl16(kg + i * 512, lk + i * 512);
#pragma unroll
    for (int i = 0; i < 4; ++i) gl16(vg + i * 512, lv + i * 512);

    for (int kt = 0; kt < 32; ++kt) {
        // DMA for this tile (issued last iteration / prologue) must have landed
        asm volatile("s_waitcnt vmcnt(0)" ::: "memory");
        __builtin_amdgcn_sched_barrier(0);

        bf16x8 ka[2][2], va[4];
        ka[0][0] = *(const bf16x8*)(lkr);
        ka[0][1] = *(const bf16x8*)(lkr + 512);
        ka[1][0] = *(const bf16x8*)(lkr + 1024);
        ka[1][1] = *(const bf16x8*)(lkr + 1536);
        va[0] = *(const bf16x8*)(lvr);
        va[1] = *(const bf16x8*)(lvr + 512);
        va[2] = *(const bf16x8*)(lvr + 1024);
        va[3] = *(const bf16x8*)(lvr + 1536);

        // reads must COMPLETE before the DMA may overwrite the slab
        asm volatile("s_waitcnt lgkmcnt(0)" ::: "memory");
        __builtin_amdgcn_sched_barrier(0);

        if (kt + 1 < 32) {
            const __bf16* kgn = kg + (size_t)(kt + 1) * 4096;
            const __bf16* vgn = vg + (size_t)(kt + 1) * 4096;
#pragma unroll
            for (int i = 0; i < 4; ++i) gl16(kgn + i * 512, lk + i * 512);
#pragma unroll
            for (int i = 0; i < 4; ++i) gl16(vgn + i * 512, lv + i * 512);
        }

#pragma unroll
        for (int nt = 0; nt < 2; ++nt) {
            f32x4 sA = {0.f, 0.f, 0.f, 0.f};
            f32x4 sB = {0.f, 0.f, 0.f, 0.f};
            sA = MFMA16(ka[0][0], qb0[nt], sA); sA = MFMA16(ka[0][1], qb1[nt], sA);
            sB = MFMA16(ka[1][0], qb0[nt], sB); sB = MFMA16(ka[1][1], qb1[nt], sB);

            // direct exp2 — no max subtraction, fully lane-local
            const float p0 = __builtin_amdgcn_exp2f(sA[0]);
            const float p1 = __builtin_amdgcn_exp2f(sA[1]);
            const float p2 = __builtin_amdgcn_exp2f(sA[2]);
            const float p3 = __builtin_amdgcn_exp2f(sA[3]);
            const float p4 = __builtin_amdgcn_exp2f(sB[0]);
            const float p5 = __builtin_amdgcn_exp2f(sB[1]);
            const float p6 = __builtin_amdgcn_exp2f(sB[2]);
            const float p7 = __builtin_amdgcn_exp2f(sB[3]);
            l[nt] += ((p0 + p1) + (p2 + p3)) + ((p4 + p5) + (p6 + p7));

            union { u32 u[4]; bf16x8 v; } pb;   // B-frag: k_mfma = quad*8+mt*4+r
            pb.u[0] = packbf(p0, p1);
            pb.u[1] = packbf(p2, p3);
            pb.u[2] = packbf(p4, p5);
            pb.u[3] = packbf(p6, p7);

#pragma unroll
            for (int dt = 0; dt < 4; ++dt)
                o[dt][nt] = MFMA16(va[dt], pb.v, o[dt][nt]);
        }
    }

    // cross-quad l reduction: sum over this wave's 32 k-rows per q=nt*16+col
#pragma unroll
    for (int nt = 0; nt < 2; ++nt) {
        l[nt] += __shfl_xor(l[nt], 16, 64);
        l[nt] += __shfl_xor(l[nt], 32, 64);
    }

    // ---- combine across the 2 wk waves per q-half ----
    __syncthreads();   // all waves done with K/V slabs
    if (quad == 0) {
#pragma unroll
        for (int nt = 0; nt < 2; ++nt)
            lbuf[wk * 64 + wq * 32 + nt * 16 + col] = l[nt];
    }
    __syncthreads();

    float scale[2];
#pragma unroll
    for (int nt = 0; nt < 2; ++nt) {
        const int ri = wq * 32 + nt * 16 + col;
        scale[nt] = 1.0f / (lbuf[ri] + lbuf[64 + ri]);
    }
#pragma unroll
    for (int dt = 0; dt < 4; ++dt)
#pragma unroll
        for (int nt = 0; nt < 2; ++nt) o[dt][nt] *= scale[nt];

    // slab (aliases K/V region — loop is done; lbuf is separate)
    if (wk == 0) {
#pragma unroll
        for (int dt = 0; dt < 4; ++dt)
#pragma unroll
            for (int nt = 0; nt < 2; ++nt)
                *(f32x4*)&slab[(wq * 32 + nt * 16 + col) * 68 + dt * 16 + quad * 4] = o[dt][nt];
    }
    __syncthreads();
    if (wk == 1) {
#pragma unroll
        for (int dt = 0; dt < 4; ++dt)
#pragma unroll
            for (int nt = 0; nt < 2; ++nt) {
                f32x4* p = (f32x4*)&slab[(wq * 32 + nt * 16 + col) * 68 + dt * 16 + quad * 4];
                *p = *p + o[dt][nt];
            }
    }
    __syncthreads();

    const int qr = tid >> 2, fq = tid & 3;
#pragma unroll
    for (int j2 = 0; j2 < 4; ++j2) {
        const f32x4 a = *(const f32x4*)&slab[qr * 68 + fq * 16 + j2 * 4];
        *(f32x4*)&out[(size_t)(b * NS + q0 + qr) * ND + h * NDH + fq * 16 + j2 * 4] = a;
    }
}

extern "C" void kernel_launch(void* const* d_in, const int* in_sizes, int n_in,
                              void* d_out, int out_size, void* d_ws, size_t ws_size,
                              hipStream_t stream) {
    (void)in_sizes; (void)n_in; (void)out_size; (void)ws_size;
    const float* x  = (const float*)d_in[0];
    const float* wq = (const float*)d_in[1];
    const float* bq = (const float*)d_in[2];
    const float* wk = (const float*)d_in[3];
    const float* bk = (const float*)d_in[4];
    const float* wv = (const float*)d_in[5];
    const float* bv = (const float*)d_in[6];
    float* out = (float*)d_out;

    __bf16* qws  = (__bf16*)d_ws;
    __bf16* kws  = qws + (size_t)NB * NH * NS * NDH;
    __bf16* vtws = kws + (size_t)NB * NH * NS * NDH;

    dim3 grid(NS / 64, NH, NB);
    proj_kernel<<<grid, 256, 0, stream>>>(x, wq, bq, wk, bk, wv, bv, qws, kws, vtws);
    attn_kernel<<<dim3(NS / 64 * NH * NB), 256, 0, stream>>>(qws, kws, vtws, out);
}

// Round 8
// 162.540 us; speedup vs baseline: 1.0527x; 1.0527x over previous
//
#include <hip/hip_runtime.h>

#define NB 4
#define NS 2048
#define ND 768
#define NH 12
#define NDH 64
#define XPITCH 72
#define SSCALE 0.18033688011112043f   // (1/sqrt(64)) * log2(e)

typedef __bf16 bf16x8 __attribute__((ext_vector_type(8)));
typedef float  f32x4  __attribute__((ext_vector_type(4)));
typedef unsigned int u32;

#define MFMA16(a, b, c) __builtin_amdgcn_mfma_f32_16x16x32_bf16(a, b, c, 0, 0, 0)

__device__ __forceinline__ u32 packbf(float a, float b) {
    u32 ua = __builtin_bit_cast(u32, a) + 0x8000u;
    u32 ub = __builtin_bit_cast(u32, b) + 0x8000u;
    return __builtin_amdgcn_perm(ub, ua, 0x07060302u);
}

__device__ __forceinline__ bf16x8 cvt8(float4 a, float4 b) {
    union { u32 u[4]; bf16x8 v; } r;
    r.u[0] = packbf(a.x, a.y); r.u[1] = packbf(a.z, a.w);
    r.u[2] = packbf(b.x, b.y); r.u[3] = packbf(b.z, b.w);
    return r.v;
}

__device__ __forceinline__ __bf16 f2bf(float f) {
    u32 u = __builtin_bit_cast(u32, f) + 0x8000u;
    unsigned short s = (unsigned short)(u >> 16);
    return __builtin_bit_cast(__bf16, s);
}

// HW DMA global->LDS, 16B per lane. LDS dest must be the WAVE-UNIFORM lane-0
// base; HW adds lane*16B. Global source is per-lane.
__device__ __forceinline__ void gl16(const __bf16* g, __bf16* l) {
    __builtin_amdgcn_global_load_lds(
        (const __attribute__((address_space(1))) unsigned int*)g,
        (__attribute__((address_space(3))) unsigned int*)l,
        16, 0, 0);
}

// ---------------------------------------------------------------------------
// Workspace layouts — ALL fragment-major, ALL R4/R7-hardware-verified:
//   Q: bh*131072 + qt*4096 + nt*1024 + j*512 + lane*8     (nt: 16-row group)
//   K: bh*131072 + sigma*2048 + mt*1024 + j*512 + lane*8  (sigma: 32-row slab)
//   V: bh*131072 + sigma*2048 + dt*512           + lane*8 (same 32-col slabs)
// Attn reads 32-row slabs sigma = kt*2 + wk. No proj change.
// ---------------------------------------------------------------------------

// ---------------------------------------------------------------------------
// Kernel 1: QKV projections — R4/R6/R7 VERBATIM (hardware-verified, coalesced
// fragment-major stores for Q, K, and V).
// ---------------------------------------------------------------------------
__global__ __launch_bounds__(256, 4) void proj_kernel(
    const float* __restrict__ x,
    const float* __restrict__ wq, const float* __restrict__ bq,
    const float* __restrict__ wk, const float* __restrict__ bk,
    const float* __restrict__ wv, const float* __restrict__ bv,
    __bf16* __restrict__ qws, __bf16* __restrict__ kws, __bf16* __restrict__ vtws)
{
    const int st = blockIdx.x, h = blockIdx.y, b = blockIdx.z;
    const int s0 = st * 64;
    const int tid = threadIdx.x;

    __shared__ __align__(16) __bf16 Xs[64 * XPITCH];
    __shared__ __align__(16) __bf16 Tv[64 * XPITCH];

    const int r = tid >> 2, f = tid & 3;
    const int lane = tid & 63, w = tid >> 6, col = lane & 15, quad = lane >> 4;

    const size_t wrow = (size_t)(h * NDH + w * 16 + col) * NDH;
    const float* wq0 = wq + wrow + quad * 8;
    const float* wk0 = wk + wrow + quad * 8;
    const float* wv0 = wv + wrow + quad * 8;
    const bf16x8 wqa0 = cvt8(*(const float4*)(wq0),      *(const float4*)(wq0 + 4));
    const bf16x8 wqa1 = cvt8(*(const float4*)(wq0 + 32), *(const float4*)(wq0 + 36));
    const bf16x8 wka0 = cvt8(*(const float4*)(wk0),      *(const float4*)(wk0 + 4));
    const bf16x8 wka1 = cvt8(*(const float4*)(wk0 + 32), *(const float4*)(wk0 + 36));
    const bf16x8 wva0 = cvt8(*(const float4*)(wv0),      *(const float4*)(wv0 + 4));
    const bf16x8 wva1 = cvt8(*(const float4*)(wv0 + 32), *(const float4*)(wv0 + 36));

    float bqs[4], bks[4], bvs[4];
#pragma unroll
    for (int rr = 0; rr < 4; ++rr) {
        const int e = h * NDH + w * 16 + quad * 4 + rr;
        bqs[rr] = bq[e] * SSCALE;
        bks[rr] = bk[e];
        bvs[rr] = bv[e];
    }

    const size_t bh = (size_t)(b * NH + h);

    {
        const float* xrow = x + (size_t)(b * NS + s0 + r) * ND + h * NDH + f * 16;
        const float4 v0 = *(const float4*)(xrow);
        const float4 v1 = *(const float4*)(xrow + 4);
        const float4 v2 = *(const float4*)(xrow + 8);
        const float4 v3 = *(const float4*)(xrow + 12);
        *(bf16x8*)&Xs[r * XPITCH + f * 16]     = cvt8(v0, v1);
        *(bf16x8*)&Xs[r * XPITCH + f * 16 + 8] = cvt8(v2, v3);
    }
    __syncthreads();

    // lane-constant pieces of the fragment-layout address (e-side):
    // e0 = w*16 + quad*4 = 32*jj + 8*qa + 4*hf
    const int e0 = w * 16 + quad * 4;
    const int jj = e0 >> 5;            // j (0/1)
    const int qa = (e0 >> 3) & 3;      // quad_attn
    const int hf = (e0 >> 2) & 1;      // which uint2 half of the 16B chunk
    const int Lf = qa * 16 + col;      // fragment lane
    const int kt = st >> 1;            // 128-row K-tile index

#pragma unroll
    for (int nt = 0; nt < 4; ++nt) {
        const bf16x8 xb0 = *(const bf16x8*)&Xs[(nt * 16 + col) * XPITCH + quad * 8];
        const bf16x8 xb1 = *(const bf16x8*)&Xs[(nt * 16 + col) * XPITCH + 32 + quad * 8];
        f32x4 aq = {0.f, 0.f, 0.f, 0.f};
        f32x4 ak = {0.f, 0.f, 0.f, 0.f};
        f32x4 av = {0.f, 0.f, 0.f, 0.f};
        aq = MFMA16(wqa0, xb0, aq); aq = MFMA16(wqa1, xb1, aq);
        ak = MFMA16(wka0, xb0, ak); ak = MFMA16(wka1, xb1, ak);
        av = MFMA16(wva0, xb0, av); av = MFMA16(wva1, xb1, av);

        union { u32 u[2]; uint2 v; } pq, pk;
        pq.u[0] = packbf(fmaf(aq[0], SSCALE, bqs[0]), fmaf(aq[1], SSCALE, bqs[1]));
        pq.u[1] = packbf(fmaf(aq[2], SSCALE, bqs[2]), fmaf(aq[3], SSCALE, bqs[3]));
        pk.u[0] = packbf(ak[0] + bks[0], ak[1] + bks[1]);
        pk.u[1] = packbf(ak[2] + bks[2], ak[3] + bks[3]);

        // fragment-major stores (R4-verified)
        const int wa = (st & 1) * 2 + (nt >> 1);   // 32-row slab within 128-tile
        const int mt = nt & 1;
        const size_t kidx = ((((((size_t)bh * 16 + kt) * 4 + wa) * 2 + mt) * 2 + jj) * 64 + Lf) * 8 + hf * 4;
        const size_t qidx = (((((size_t)bh * 32 + st) * 4 + nt) * 2 + jj) * 64 + Lf) * 8 + hf * 4;
        *(uint2*)(kws + kidx) = pk.v;
        *(uint2*)(qws + qidx) = pq.v;

        const int pos = ((nt >> 1) << 5) + ((col >> 2) << 3) + ((nt & 1) << 2) + (col & 3);
#pragma unroll
        for (int rr = 0; rr < 4; ++rr)
            Tv[(w * 16 + quad * 4 + rr) * XPITCH + pos] = f2bf(av[rr] + bvs[rr]);
    }
    __syncthreads();

    {
        const uint4 v0 = *(const uint4*)&Tv[r * XPITCH + f * 16];
        const uint4 v1 = *(const uint4*)&Tv[r * XPITCH + f * 16 + 8];
        // thread (r,f) holds V^T[d=r][s0 + f*16 .. +15] = two 8-s chunks (R4-verified)
        const int wv_ = (st & 1) * 2 + (f >> 1);
        const int dtv = r >> 4;
        const int colv = r & 15;
        const int L0 = ((f & 1) * 2 + 0) * 16 + colv;
        const int L1 = ((f & 1) * 2 + 1) * 16 + colv;
        const size_t vbase = (((size_t)bh * 16 + kt) * 4 + wv_) * 4 + dtv;
        *(uint4*)(vtws + (vbase * 64 + L0) * 8) = v0;
        *(uint4*)(vtws + (vbase * 64 + L1) * 8) = v1;
    }
}

// ---------------------------------------------------------------------------
// Kernel 2: flash attention WITHOUT online max (scores statically bounded;
// exp2 direct). 2x2 wave decomposition (R7-proven: 32q x 32k per wave,
// acc 32 AGPR, (256,4) spill-free).
//
// NEW this round — counted-vmcnt pipeline (T3/T4), replacing R7's two full
// drains per iteration (R7 arithmetic: ~2300 cyc wall per wave-iter vs
// ~600 busy = 75% latency stall):
//   K: DMA into DOUBLE-BUFFERED wave-private LDS (2 x 4KB/wave = 32KB/block,
//      still 4 blocks/CU). DMA(kt+1) -> other buffer => NO read-completion
//      constraint, NO vmcnt(0) in the loop.
//   V: DIRECT global->reg (fragment-major, R4/R7-verified addresses), va
//      live only across PV.
//   Queue discipline (vmcnt retires in issue order, m135):
//     iter top:  issue va(kt)x4            queue=[K(kt)x4, va(kt)x4]
//                vmcnt(4)  => K(kt) landed
//                ds_read ka x4 (buf cur)
//                issue K-DMA(kt+1)x4 -> buf cur^1
//                QK + exp2 + pack (both nt) queue=[va(kt)x4, K(kt+1)x4]
//                vmcnt(4)  => va landed, K(kt+1) STILL IN FLIGHT
//                PV (both nt)
//     last iter: vmcnt(0) (no DMA behind va). sched_barrier(0) pins each
//     load set on the correct side of its wait.
// Registers: qb16 + acc32 + ka8 + va8 + pb8 + addr/temps ~= 100 <= 128.
// s_setprio OUT (R3). XCD-bijective decode kept (R3: FETCH 109->24MB).
// LDS: K dbuf [0,32768) | lbuf [32768,33280); epilogue slab aliases
// [0,17408). Total 33280 B -> 4 blocks = 133 KB <= 160 KB.
// ---------------------------------------------------------------------------
__global__ __launch_bounds__(256, 4) void attn_kernel(
    const __bf16* __restrict__ qws, const __bf16* __restrict__ kws,
    const __bf16* __restrict__ vtws, float* __restrict__ out)
{
    // XCD-aware bijective decode: bid = xcd + 8*j, j = 32*(group within XCD) + qt
    const int bid = blockIdx.x;
    const int xcd = bid & 7;
    const int j   = bid >> 3;            // 0..191
    const int g   = xcd * 6 + (j >> 5);  // (b,h) group 0..47
    const int qt  = j & 31;
    const int h   = g % NH;
    const int b   = g / NH;

    const int q0 = qt * 64;
    const int tid = threadIdx.x;

    __shared__ __align__(16) unsigned char smem[33280];
    __bf16* ldsK = (__bf16*)smem;                // 2 bufs x 4 waves x 4KB = 32 KB
    float* slab  = (float*)smem;                 // 64 x 68 f32 (epilogue, aliases)
    float* lbuf  = (float*)(smem + 32768);       // 128 f32 (no alias)

    const size_t bh = (size_t)(b * NH + h);
    const int lane = tid & 63, w = tid >> 6, col = lane & 15, quad = lane >> 4;
    const int wq = w >> 1, wk = w & 1;

    // Q fragments: this wave's 32 q-rows (nt in {0,1} -> rows wq*32+nt*16+col)
    bf16x8 qb0[2], qb1[2];
    {
        const __bf16* qp = qws + (size_t)bh * 131072 + (size_t)qt * 4096
                         + wq * 2048 + lane * 8;
#pragma unroll
        for (int nt = 0; nt < 2; ++nt) {
            qb0[nt] = *(const bf16x8*)(qp + nt * 1024);
            qb1[nt] = *(const bf16x8*)(qp + nt * 1024 + 512);
        }
    }

    // fragment-major global bases: slab sigma = kt*2 + wk (32 rows each)
    const __bf16* kg = kws  + (size_t)bh * 131072 + wk * 2048 + lane * 8;  // per-lane src
    const __bf16* vg = vtws + (size_t)bh * 131072 + wk * 2048 + lane * 8;
    __bf16* lk0 = ldsK + w * 2048;               // wave-uniform DMA dest, buf0
    __bf16* lk1 = ldsK + 8192 + w * 2048;        // buf1
    const __bf16* lkr0 = lk0 + lane * 8;         // per-lane read base
    const __bf16* lkr1 = lk1 + lane * 8;

    float l[2] = {0.f, 0.f};
    f32x4 o[4][2];
#pragma unroll
    for (int dt = 0; dt < 4; ++dt)
#pragma unroll
        for (int nt = 0; nt < 2; ++nt) o[dt][nt] = (f32x4){0.f, 0.f, 0.f, 0.f};

    // one iteration: kt, read buf LKRD, DMA(kt+1)->LKN if DMA_C, PV-wait literal
#define ATTN_ITER(ktv, LKRD, LKN, DMA_C, PV_LAST) do {                        \
        const __bf16* _vp = vg + (size_t)(ktv) * 4096;                        \
        const bf16x8 va0 = *(const bf16x8*)(_vp);                             \
        const bf16x8 va1 = *(const bf16x8*)(_vp + 512);                       \
        const bf16x8 va2 = *(const bf16x8*)(_vp + 1024);                      \
        const bf16x8 va3 = *(const bf16x8*)(_vp + 1536);                      \
        __builtin_amdgcn_sched_barrier(0);                                    \
        asm volatile("s_waitcnt vmcnt(4)" ::: "memory");                      \
        __builtin_amdgcn_sched_barrier(0);                                    \
        const bf16x8 ka00 = *(const bf16x8*)(LKRD);                           \
        const bf16x8 ka01 = *(const bf16x8*)(LKRD + 512);                     \
        const bf16x8 ka10 = *(const bf16x8*)(LKRD + 1024);                    \
        const bf16x8 ka11 = *(const bf16x8*)(LKRD + 1536);                    \
        if (DMA_C) {                                                          \
            const __bf16* _kn = kg + (size_t)((ktv) + 1) * 4096;              \
            gl16(_kn,        LKN);        gl16(_kn + 512,  LKN + 512);        \
            gl16(_kn + 1024, LKN + 1024); gl16(_kn + 1536, LKN + 1536);       \
        }                                                                     \
        union { u32 u[4]; bf16x8 v; } pb[2];                                  \
        _Pragma("unroll")                                                     \
        for (int nt = 0; nt < 2; ++nt) {                                      \
            f32x4 sA = {0.f, 0.f, 0.f, 0.f};                                  \
            f32x4 sB = {0.f, 0.f, 0.f, 0.f};                                  \
            sA = MFMA16(ka00, qb0[nt], sA); sA = MFMA16(ka01, qb1[nt], sA);   \
            sB = MFMA16(ka10, qb0[nt], sB); sB = MFMA16(ka11, qb1[nt], sB);   \
            const float p0 = __builtin_amdgcn_exp2f(sA[0]);                   \
            const float p1 = __builtin_amdgcn_exp2f(sA[1]);                   \
            const float p2 = __builtin_amdgcn_exp2f(sA[2]);                   \
            const float p3 = __builtin_amdgcn_exp2f(sA[3]);                   \
            const float p4 = __builtin_amdgcn_exp2f(sB[0]);                   \
            const float p5 = __builtin_amdgcn_exp2f(sB[1]);                   \
            const float p6 = __builtin_amdgcn_exp2f(sB[2]);                   \
            const float p7 = __builtin_amdgcn_exp2f(sB[3]);                   \
            l[nt] += ((p0 + p1) + (p2 + p3)) + ((p4 + p5) + (p6 + p7));       \
            pb[nt].u[0] = packbf(p0, p1);                                     \
            pb[nt].u[1] = packbf(p2, p3);                                     \
            pb[nt].u[2] = packbf(p4, p5);                                     \
            pb[nt].u[3] = packbf(p6, p7);                                     \
        }                                                                     \
        __builtin_amdgcn_sched_barrier(0);                                    \
        if (PV_LAST) { asm volatile("s_waitcnt vmcnt(0)" ::: "memory"); }     \
        else         { asm volatile("s_waitcnt vmcnt(4)" ::: "memory"); }     \
        __builtin_amdgcn_sched_barrier(0);                                    \
        _Pragma("unroll")                                                     \
        for (int nt = 0; nt < 2; ++nt) {                                      \
            o[0][nt] = MFMA16(va0, pb[nt].v, o[0][nt]);                       \
            o[1][nt] = MFMA16(va1, pb[nt].v, o[1][nt]);                       \
            o[2][nt] = MFMA16(va2, pb[nt].v, o[2][nt]);                       \
            o[3][nt] = MFMA16(va3, pb[nt].v, o[3][nt]);                       \
        }                                                                     \
    } while (0)

    // ---- prologue: DMA K tile 0 -> buf0 (queue = [K0 x4]) ----
    gl16(kg,        lk0);        gl16(kg + 512,  lk0 + 512);
    gl16(kg + 1024, lk0 + 1024); gl16(kg + 1536, lk0 + 1536);

    for (int kt2 = 0; kt2 < 30; kt2 += 2) {
        ATTN_ITER(kt2,     lkr0, lk1, true, false);   // read buf0, DMA->buf1
        ATTN_ITER(kt2 + 1, lkr1, lk0, true, false);   // read buf1, DMA->buf0
    }
    ATTN_ITER(30, lkr0, lk1, true,  false);           // DMA(31)->buf1
    ATTN_ITER(31, lkr1, lk0, false, true);            // no DMA; final vmcnt(0)
#undef ATTN_ITER

    // cross-quad l reduction: sum over this wave's 32 k-rows per q=nt*16+col
#pragma unroll
    for (int nt = 0; nt < 2; ++nt) {
        l[nt] += __shfl_xor(l[nt], 16, 64);
        l[nt] += __shfl_xor(l[nt], 32, 64);
    }

    // ---- combine across the 2 wk waves per q-half ----
    __syncthreads();   // all waves done with K slabs
    if (quad == 0) {
#pragma unroll
        for (int nt = 0; nt < 2; ++nt)
            lbuf[wk * 64 + wq * 32 + nt * 16 + col] = l[nt];
    }
    __syncthreads();

    float scale[2];
#pragma unroll
    for (int nt = 0; nt < 2; ++nt) {
        const int ri = wq * 32 + nt * 16 + col;
        scale[nt] = 1.0f / (lbuf[ri] + lbuf[64 + ri]);
    }
#pragma unroll
    for (int dt = 0; dt < 4; ++dt)
#pragma unroll
        for (int nt = 0; nt < 2; ++nt) o[dt][nt] *= scale[nt];

    // slab (aliases K region — loop is done; lbuf is separate)
    if (wk == 0) {
#pragma unroll
        for (int dt = 0; dt < 4; ++dt)
#pragma unroll
            for (int nt = 0; nt < 2; ++nt)
                *(f32x4*)&slab[(wq * 32 + nt * 16 + col) * 68 + dt * 16 + quad * 4] = o[dt][nt];
    }
    __syncthreads();
    if (wk == 1) {
#pragma unroll
        for (int dt = 0; dt < 4; ++dt)
#pragma unroll
            for (int nt = 0; nt < 2; ++nt) {
                f32x4* p = (f32x4*)&slab[(wq * 32 + nt * 16 + col) * 68 + dt * 16 + quad * 4];
                *p = *p + o[dt][nt];
            }
    }
    __syncthreads();

    const int qr = tid >> 2, fq = tid & 3;
#pragma unroll
    for (int j2 = 0; j2 < 4; ++j2) {
        const f32x4 a = *(const f32x4*)&slab[qr * 68 + fq * 16 + j2 * 4];
        *(f32x4*)&out[(size_t)(b * NS + q0 + qr) * ND + h * NDH + fq * 16 + j2 * 4] = a;
    }
}

extern "C" void kernel_launch(void* const* d_in, const int* in_sizes, int n_in,
                              void* d_out, int out_size, void* d_ws, size_t ws_size,
                              hipStream_t stream) {
    (void)in_sizes; (void)n_in; (void)out_size; (void)ws_size;
    const float* x  = (const float*)d_in[0];
    const float* wq = (const float*)d_in[1];
    const float* bq = (const float*)d_in[2];
    const float* wk = (const float*)d_in[3];
    const float* bk = (const float*)d_in[4];
    const float* wv = (const float*)d_in[5];
    const float* bv = (const float*)d_in[6];
    float* out = (float*)d_out;

    __bf16* qws  = (__bf16*)d_ws;
    __bf16* kws  = qws + (size_t)NB * NH * NS * NDH;
    __bf16* vtws = kws + (size_t)NB * NH * NS * NDH;

    dim3 grid(NS / 64, NH, NB);
    proj_kernel<<<grid, 256, 0, stream>>>(x, wq, bq, wk, bk, wv, bv, qws, kws, vtws);
    attn_kernel<<<dim3(NS / 64 * NH * NB), 256, 0, stream>>>(qws, kws, vtws, out);
}